// Round 1
// baseline (1310.467 us; speedup 1.0000x reference)
//
#include <hip/hip_runtime.h>
#include <hip/hip_bf16.h>

#define HW 65536
// layouts in workspace (bf16, channel-major per (b,h) slice):
//   ql, qr : [1024 slices][64 ch][256 px]
//   vl, vr : [1024 slices][32 ch][256 px]

__global__ __launch_bounds__(256) void proj_kernel(
    const float* __restrict__ xr, const float* __restrict__ xh,
    const float* __restrict__ lnw, const float* __restrict__ lnb,
    const float* __restrict__ wl1, const float* __restrict__ bl1,
    const float* __restrict__ wr1, const float* __restrict__ br1,
    const float* __restrict__ wl2, const float* __restrict__ bl2,
    const float* __restrict__ wr2, const float* __restrict__ br2,
    const float* __restrict__ wlres, const float* __restrict__ blres,
    const float* __restrict__ wrres, const float* __restrict__ brres,
    __hip_bfloat16* __restrict__ ql, __hip_bfloat16* __restrict__ qr,
    __hip_bfloat16* __restrict__ vl, __hip_bfloat16* __restrict__ vr,
    float* __restrict__ out)
{
    const int bh = blockIdx.x;        // (b*256 + h)
    const int b  = bh >> 8;
    const int h  = bh & 255;
    const int w  = threadIdx.x;       // pixel within row
    const size_t base = (size_t)b * 64 * HW + (size_t)h * 256 + w;

    float x[64];
    // ---- left input + LN stats ----
    const float* xp = xr + base;
    float sum = 0.f;
#pragma unroll
    for (int c = 0; c < 64; ++c) { x[c] = xp[(size_t)c * HW]; sum += x[c]; }
    const float mu = sum * (1.f / 64.f);
    float var = 0.f;
#pragma unroll
    for (int c = 0; c < 64; ++c) { float d = x[c] - mu; var = fmaf(d, d, var); }
    const float rstd = rsqrtf(var * (1.f / 64.f) + 1e-6f);

    const size_t qbase = (size_t)bh * 16384;  // 64*256
    const size_t vbase = (size_t)bh * 8192;   // 32*256
    float* outp = out + base;
    float acc[8];

    // ---- v_l = W_l2 @ x + b_l2 (32 outs) ----
    for (int og = 0; og < 4; ++og) {
#pragma unroll
        for (int i = 0; i < 8; ++i) acc[i] = bl2[og*8+i];
#pragma unroll
        for (int c = 0; c < 64; ++c) {
            const float xv = x[c];
#pragma unroll
            for (int i = 0; i < 8; ++i) acc[i] = fmaf(wl2[(og*8+i)*64+c], xv, acc[i]);
        }
#pragma unroll
        for (int i = 0; i < 8; ++i)
            vl[vbase + (size_t)(og*8+i)*256 + w] = __float2bfloat16(acc[i]);
    }
    // ---- res_l = W_lres @ x + b_lres -> out channels 0..31 ----
    for (int og = 0; og < 4; ++og) {
#pragma unroll
        for (int i = 0; i < 8; ++i) acc[i] = blres[og*8+i];
#pragma unroll
        for (int c = 0; c < 64; ++c) {
            const float xv = x[c];
#pragma unroll
            for (int i = 0; i < 8; ++i) acc[i] = fmaf(wlres[(og*8+i)*64+c], xv, acc[i]);
        }
#pragma unroll
        for (int i = 0; i < 8; ++i) outp[(size_t)(og*8+i)*HW] = acc[i];
    }
    // ---- x <- LayerNorm(x) ----
#pragma unroll
    for (int c = 0; c < 64; ++c) x[c] = fmaf((x[c] - mu) * rstd, lnw[c], lnb[c]);
    // ---- q_l = W_l1 @ ln(x) + b_l1 (64 outs) ----
    for (int og = 0; og < 8; ++og) {
#pragma unroll
        for (int i = 0; i < 8; ++i) acc[i] = bl1[og*8+i];
#pragma unroll
        for (int c = 0; c < 64; ++c) {
            const float xv = x[c];
#pragma unroll
            for (int i = 0; i < 8; ++i) acc[i] = fmaf(wl1[(og*8+i)*64+c], xv, acc[i]);
        }
#pragma unroll
        for (int i = 0; i < 8; ++i)
            ql[qbase + (size_t)(og*8+i)*256 + w] = __float2bfloat16(acc[i]);
    }

    // ---- right input ----
    const float* xhp = xh + base;
#pragma unroll
    for (int c = 0; c < 64; ++c) x[c] = xhp[(size_t)c * HW];
    // ---- q_r (64 outs) ----
    for (int og = 0; og < 8; ++og) {
#pragma unroll
        for (int i = 0; i < 8; ++i) acc[i] = br1[og*8+i];
#pragma unroll
        for (int c = 0; c < 64; ++c) {
            const float xv = x[c];
#pragma unroll
            for (int i = 0; i < 8; ++i) acc[i] = fmaf(wr1[(og*8+i)*64+c], xv, acc[i]);
        }
#pragma unroll
        for (int i = 0; i < 8; ++i)
            qr[qbase + (size_t)(og*8+i)*256 + w] = __float2bfloat16(acc[i]);
    }
    // ---- v_r (32 outs) ----
    for (int og = 0; og < 4; ++og) {
#pragma unroll
        for (int i = 0; i < 8; ++i) acc[i] = br2[og*8+i];
#pragma unroll
        for (int c = 0; c < 64; ++c) {
            const float xv = x[c];
#pragma unroll
            for (int i = 0; i < 8; ++i) acc[i] = fmaf(wr2[(og*8+i)*64+c], xv, acc[i]);
        }
#pragma unroll
        for (int i = 0; i < 8; ++i)
            vr[vbase + (size_t)(og*8+i)*256 + w] = __float2bfloat16(acc[i]);
    }
    // ---- res_r -> out channels 32..63 ----
    for (int og = 0; og < 4; ++og) {
#pragma unroll
        for (int i = 0; i < 8; ++i) acc[i] = brres[og*8+i];
#pragma unroll
        for (int c = 0; c < 64; ++c) {
            const float xv = x[c];
#pragma unroll
            for (int i = 0; i < 8; ++i) acc[i] = fmaf(wrres[(og*8+i)*64+c], xv, acc[i]);
        }
#pragma unroll
        for (int i = 0; i < 8; ++i) outp[(size_t)(32 + og*8+i)*HW] = acc[i];
    }
}

// One block per (b,h,direction). dir 0: Q=q_l,K=q_r,V=v_r (r2l, coef=beta, out ch 0..31)
//                                dir 1: Q=q_r,K=q_l,V=v_l (l2r, coef=gamma, out ch 32..63)
// K,V layouts are channel-major [64][256] / [32][256] per slice.
__global__ __launch_bounds__(256) void attn_kernel(
    const __hip_bfloat16* __restrict__ ql, const __hip_bfloat16* __restrict__ qr,
    const __hip_bfloat16* __restrict__ vl, const __hip_bfloat16* __restrict__ vr,
    const float* __restrict__ beta, const float* __restrict__ gamma,
    float* __restrict__ out)
{
    __shared__ __align__(16) float Ks[64 * 256];  // 64 KB, [c][v]
    __shared__ __align__(16) float Vs[32 * 256];  // 32 KB, [c][v]

    const int bh  = blockIdx.x;
    const int dir = blockIdx.y;
    const int b   = bh >> 8;
    const int h   = bh & 255;
    const int tid = threadIdx.x;

    const __hip_bfloat16* Q = (dir == 0 ? ql : qr) + (size_t)bh * 16384;
    const __hip_bfloat16* K = (dir == 0 ? qr : ql) + (size_t)bh * 16384;
    const __hip_bfloat16* V = (dir == 0 ? vr : vl) + (size_t)bh * 8192;
    const float* coef = (dir == 0) ? beta : gamma;

    // stage K, V into LDS as f32 (vectorized 16B loads, linear layout preserved)
    const float4* K4 = reinterpret_cast<const float4*>(K);
    for (int i = tid; i < 2048; i += 256) {
        float4 t = K4[i];
        const __hip_bfloat16* hp = reinterpret_cast<const __hip_bfloat16*>(&t);
#pragma unroll
        for (int k = 0; k < 8; ++k) Ks[i*8 + k] = __bfloat162float(hp[k]);
    }
    const float4* V4 = reinterpret_cast<const float4*>(V);
    for (int i = tid; i < 1024; i += 256) {
        float4 t = V4[i];
        const __hip_bfloat16* hp = reinterpret_cast<const __hip_bfloat16*>(&t);
#pragma unroll
        for (int k = 0; k < 8; ++k) Vs[i*8 + k] = __bfloat162float(hp[k]);
    }
    __syncthreads();

    // my query row (pixel tid): coalesced channel-major reads
    float q[64];
#pragma unroll
    for (int c = 0; c < 64; ++c) q[c] = __bfloat162float(Q[c*256 + tid]);

    float m = -3.0e38f, l = 0.f;
    float acc[32];
#pragma unroll
    for (int c = 0; c < 32; ++c) acc[c] = 0.f;

    for (int v0 = 0; v0 < 256; v0 += 8) {
        float s[8];
#pragma unroll
        for (int j = 0; j < 8; ++j) s[j] = 0.f;
#pragma unroll
        for (int c = 0; c < 64; ++c) {
            const float qc = q[c];
            const float4* kc = reinterpret_cast<const float4*>(&Ks[c*256 + v0]);
            const float4 ka = kc[0], kb = kc[1];
            s[0] = fmaf(qc, ka.x, s[0]); s[1] = fmaf(qc, ka.y, s[1]);
            s[2] = fmaf(qc, ka.z, s[2]); s[3] = fmaf(qc, ka.w, s[3]);
            s[4] = fmaf(qc, kb.x, s[4]); s[5] = fmaf(qc, kb.y, s[5]);
            s[6] = fmaf(qc, kb.z, s[6]); s[7] = fmaf(qc, kb.w, s[7]);
        }
        float bm = m;
#pragma unroll
        for (int j = 0; j < 8; ++j) { s[j] *= 0.125f; bm = fmaxf(bm, s[j]); }
        const float resc = __expf(m - bm);
        m = bm;
        l *= resc;
#pragma unroll
        for (int c = 0; c < 32; ++c) acc[c] *= resc;
        float p[8];
#pragma unroll
        for (int j = 0; j < 8; ++j) { p[j] = __expf(s[j] - m); l += p[j]; }
#pragma unroll
        for (int c = 0; c < 32; ++c) {
            const float4* vc = reinterpret_cast<const float4*>(&Vs[c*256 + v0]);
            const float4 va = vc[0], vb = vc[1];
            float a = acc[c];
            a = fmaf(p[0], va.x, a); a = fmaf(p[1], va.y, a);
            a = fmaf(p[2], va.z, a); a = fmaf(p[3], va.w, a);
            a = fmaf(p[4], vb.x, a); a = fmaf(p[5], vb.y, a);
            a = fmaf(p[6], vb.z, a); a = fmaf(p[7], vb.w, a);
            acc[c] = a;
        }
    }
    const float inv = 1.f / l;
    const size_t obase = ((size_t)(b*64 + (dir ? 32 : 0)) * 256 + h) * 256 + tid;
#pragma unroll
    for (int c = 0; c < 32; ++c) {
        out[obase + (size_t)c * HW] += coef[c] * acc[c] * inv;
    }
}

extern "C" void kernel_launch(void* const* d_in, const int* in_sizes, int n_in,
                              void* d_out, int out_size, void* d_ws, size_t ws_size,
                              hipStream_t stream) {
    (void)in_sizes; (void)n_in; (void)out_size; (void)ws_size;
    const float* xr    = (const float*)d_in[0];
    const float* xh    = (const float*)d_in[1];
    const float* lnw   = (const float*)d_in[2];
    const float* lnb   = (const float*)d_in[3];
    const float* wl1   = (const float*)d_in[4];
    const float* bl1   = (const float*)d_in[5];
    const float* wr1   = (const float*)d_in[6];
    const float* br1   = (const float*)d_in[7];
    const float* wl2   = (const float*)d_in[8];
    const float* bl2   = (const float*)d_in[9];
    const float* wr2   = (const float*)d_in[10];
    const float* br2   = (const float*)d_in[11];
    const float* wlres = (const float*)d_in[12];
    const float* blres = (const float*)d_in[13];
    const float* wrres = (const float*)d_in[14];
    const float* brres = (const float*)d_in[15];
    const float* beta  = (const float*)d_in[16];
    const float* gamma = (const float*)d_in[17];
    float* out = (float*)d_out;

    __hip_bfloat16* ql = (__hip_bfloat16*)d_ws;
    __hip_bfloat16* qr = ql + (size_t)1024 * 16384;
    __hip_bfloat16* vl = qr + (size_t)1024 * 16384;
    __hip_bfloat16* vr = vl + (size_t)1024 * 8192;

    proj_kernel<<<dim3(1024), dim3(256), 0, stream>>>(
        xr, xh, lnw, lnb, wl1, bl1, wr1, br1, wl2, bl2, wr2, br2,
        wlres, blres, wrres, brres, ql, qr, vl, vr, out);
    attn_kernel<<<dim3(1024, 2), dim3(256), 0, stream>>>(
        ql, qr, vl, vr, beta, gamma, out);
}

// Round 2
// 471.741 us; speedup vs baseline: 2.7779x; 2.7779x over previous
//
#include <hip/hip_runtime.h>
#include <hip/hip_bf16.h>

#define HW 65536

typedef short short8 __attribute__((ext_vector_type(8)));
typedef float f32x4 __attribute__((ext_vector_type(4)));

__device__ __forceinline__ unsigned short f2bf(float x) {
    return __builtin_bit_cast(unsigned short, __float2bfloat16(x));
}

// workspace layouts:
//   ql, qr : [1024 slices][256 px][64 ch]  bf16 (px-major, for MFMA fragments)
//   vl, vr : [1024 slices][32 ch][256 px]  bf16 (channel-major, for PV B-fragments)

__global__ __launch_bounds__(256) void proj_kernel(
    const float* __restrict__ xr, const float* __restrict__ xh,
    const float* __restrict__ lnw, const float* __restrict__ lnb,
    const float* __restrict__ wl1, const float* __restrict__ bl1,
    const float* __restrict__ wr1, const float* __restrict__ br1,
    const float* __restrict__ wl2, const float* __restrict__ bl2,
    const float* __restrict__ wr2, const float* __restrict__ br2,
    const float* __restrict__ wlres, const float* __restrict__ blres,
    const float* __restrict__ wrres, const float* __restrict__ brres,
    __hip_bfloat16* __restrict__ ql, __hip_bfloat16* __restrict__ qr,
    __hip_bfloat16* __restrict__ vl, __hip_bfloat16* __restrict__ vr,
    float* __restrict__ out)
{
    const int bh = blockIdx.x;        // (b*256 + h)
    const int b  = bh >> 8;
    const int h  = bh & 255;
    const int w  = threadIdx.x;       // pixel within row
    const size_t base = (size_t)b * 64 * HW + (size_t)h * 256 + w;

    float x[64];
    const float* xp = xr + base;
    float sum = 0.f;
#pragma unroll
    for (int c = 0; c < 64; ++c) { x[c] = xp[(size_t)c * HW]; sum += x[c]; }
    const float mu = sum * (1.f / 64.f);
    float var = 0.f;
#pragma unroll
    for (int c = 0; c < 64; ++c) { float d = x[c] - mu; var = fmaf(d, d, var); }
    const float rstd = rsqrtf(var * (1.f / 64.f) + 1e-6f);

    const size_t qbase = (size_t)bh * 16384;  // 256*64
    const size_t vbase = (size_t)bh * 8192;   // 32*256
    float* outp = out + base;
    float acc[8];

    // ---- v_l (32 outs, channel-major) ----
    for (int og = 0; og < 4; ++og) {
#pragma unroll
        for (int i = 0; i < 8; ++i) acc[i] = bl2[og*8+i];
#pragma unroll
        for (int c = 0; c < 64; ++c) {
            const float xv = x[c];
#pragma unroll
            for (int i = 0; i < 8; ++i) acc[i] = fmaf(wl2[(og*8+i)*64+c], xv, acc[i]);
        }
#pragma unroll
        for (int i = 0; i < 8; ++i)
            vl[vbase + (size_t)(og*8+i)*256 + w] = __float2bfloat16(acc[i]);
    }
    // ---- res_l -> out channels 0..31 ----
    for (int og = 0; og < 4; ++og) {
#pragma unroll
        for (int i = 0; i < 8; ++i) acc[i] = blres[og*8+i];
#pragma unroll
        for (int c = 0; c < 64; ++c) {
            const float xv = x[c];
#pragma unroll
            for (int i = 0; i < 8; ++i) acc[i] = fmaf(wlres[(og*8+i)*64+c], xv, acc[i]);
        }
#pragma unroll
        for (int i = 0; i < 8; ++i) outp[(size_t)(og*8+i)*HW] = acc[i];
    }
    // ---- x <- LayerNorm(x) ----
#pragma unroll
    for (int c = 0; c < 64; ++c) x[c] = fmaf((x[c] - mu) * rstd, lnw[c], lnb[c]);
    // ---- q_l (64 outs, px-major) ----
    {
        uint4* q16 = (uint4*)(ql + qbase + (size_t)w * 64);
        for (int og = 0; og < 8; ++og) {
#pragma unroll
            for (int i = 0; i < 8; ++i) acc[i] = bl1[og*8+i];
#pragma unroll
            for (int c = 0; c < 64; ++c) {
                const float xv = x[c];
#pragma unroll
                for (int i = 0; i < 8; ++i) acc[i] = fmaf(wl1[(og*8+i)*64+c], xv, acc[i]);
            }
            uint4 u;
            u.x = f2bf(acc[0]) | ((unsigned)f2bf(acc[1]) << 16);
            u.y = f2bf(acc[2]) | ((unsigned)f2bf(acc[3]) << 16);
            u.z = f2bf(acc[4]) | ((unsigned)f2bf(acc[5]) << 16);
            u.w = f2bf(acc[6]) | ((unsigned)f2bf(acc[7]) << 16);
            q16[og] = u;
        }
    }

    // ---- right input ----
    const float* xhp = xh + base;
#pragma unroll
    for (int c = 0; c < 64; ++c) x[c] = xhp[(size_t)c * HW];
    // ---- q_r (64 outs, px-major) ----
    {
        uint4* q16 = (uint4*)(qr + qbase + (size_t)w * 64);
        for (int og = 0; og < 8; ++og) {
#pragma unroll
            for (int i = 0; i < 8; ++i) acc[i] = br1[og*8+i];
#pragma unroll
            for (int c = 0; c < 64; ++c) {
                const float xv = x[c];
#pragma unroll
                for (int i = 0; i < 8; ++i) acc[i] = fmaf(wr1[(og*8+i)*64+c], xv, acc[i]);
            }
            uint4 u;
            u.x = f2bf(acc[0]) | ((unsigned)f2bf(acc[1]) << 16);
            u.y = f2bf(acc[2]) | ((unsigned)f2bf(acc[3]) << 16);
            u.z = f2bf(acc[4]) | ((unsigned)f2bf(acc[5]) << 16);
            u.w = f2bf(acc[6]) | ((unsigned)f2bf(acc[7]) << 16);
            q16[og] = u;
        }
    }
    // ---- v_r (32 outs, channel-major) ----
    for (int og = 0; og < 4; ++og) {
#pragma unroll
        for (int i = 0; i < 8; ++i) acc[i] = br2[og*8+i];
#pragma unroll
        for (int c = 0; c < 64; ++c) {
            const float xv = x[c];
#pragma unroll
            for (int i = 0; i < 8; ++i) acc[i] = fmaf(wr2[(og*8+i)*64+c], xv, acc[i]);
        }
#pragma unroll
        for (int i = 0; i < 8; ++i)
            vr[vbase + (size_t)(og*8+i)*256 + w] = __float2bfloat16(acc[i]);
    }
    // ---- res_r -> out channels 32..63 ----
    for (int og = 0; og < 4; ++og) {
#pragma unroll
        for (int i = 0; i < 8; ++i) acc[i] = brres[og*8+i];
#pragma unroll
        for (int c = 0; c < 64; ++c) {
            const float xv = x[c];
#pragma unroll
            for (int i = 0; i < 8; ++i) acc[i] = fmaf(wrres[(og*8+i)*64+c], xv, acc[i]);
        }
#pragma unroll
        for (int i = 0; i < 8; ++i) outp[(size_t)(32 + og*8+i)*HW] = acc[i];
    }
}

// MFMA flash attention. One block per (bh, dir); 4 waves; each wave does 4
// chunks of 16 query rows. dir 0: Q=q_l,K=q_r,V=v_r (beta, out ch 0..31)
//                          dir 1: Q=q_r,K=q_l,V=v_l (gamma, out ch 32..63)
__global__ __launch_bounds__(256) void attn_kernel(
    const __hip_bfloat16* __restrict__ ql, const __hip_bfloat16* __restrict__ qr,
    const __hip_bfloat16* __restrict__ vl, const __hip_bfloat16* __restrict__ vr,
    const float* __restrict__ beta, const float* __restrict__ gamma,
    float* __restrict__ out)
{
    // Ks: [0,32768)      K px-major [256 key][64 ch] bf16, 16B-block cb at key*8 + (cb^(key&7))
    // Vs: [32768,49152)  V ch-major [32 ch][256 key] bf16, 16B-block vb at ch*32 + (vb^(ch&7))
    // P : [49152,81920)  per-wave 8KB: [16 row][256 key] bf16, 16B-block pb at row*32 + (pb^(row&7))
    __shared__ __align__(16) unsigned char smem[81920];

    const int bh   = blockIdx.x;
    const int dir  = blockIdx.y;
    const int tid  = threadIdx.x;
    const int wv   = tid >> 6;
    const int lane = tid & 63;
    const int g    = lane >> 4;   // 16-lane group
    const int lr   = lane & 15;

    const __hip_bfloat16* Qg = (dir ? qr : ql) + (size_t)bh * 16384;
    const __hip_bfloat16* Kg = (dir ? ql : qr) + (size_t)bh * 16384;
    const __hip_bfloat16* Vg = (dir ? vl : vr) + (size_t)bh * 8192;
    const float* coef = dir ? gamma : beta;

    uint4* Ks16 = (uint4*)smem;
    uint4* Vs16 = (uint4*)(smem + 32768);
    unsigned char* Pw = smem + 49152 + wv * 8192;

    // ---- stage K (2048 16B blocks) and V (1024 blocks), swizzled ----
    const uint4* Kg16 = (const uint4*)Kg;
    const uint4* Vg16 = (const uint4*)Vg;
#pragma unroll
    for (int it = 0; it < 8; ++it) {
        int i = tid + it * 256;
        int px = i >> 3, cb = i & 7;
        Ks16[px * 8 + (cb ^ (px & 7))] = Kg16[i];
    }
#pragma unroll
    for (int it = 0; it < 4; ++it) {
        int i = tid + it * 256;
        int ch = i >> 5, vb = i & 31;
        Vs16[ch * 32 + (vb ^ (ch & 7))] = Vg16[i];
    }
    __syncthreads();

    const int b = bh >> 8, h = bh & 255;
    const size_t obase = ((size_t)(b * 64 + dir * 32)) * HW + (size_t)h * 256;
    const float cs = 0.125f * 1.44269504088896f;  // scale * log2(e)

    for (int c = 0; c < 4; ++c) {
        const int row0 = c * 64 + wv * 16;   // this wave's 16 query rows
        // Q fragments from global (px-major): lane -> q-row lr, ch 8g..8g+7 (+32)
        short8 qf0, qf1;
        {
            const uint4* q16 = (const uint4*)(Qg + (size_t)(row0 + lr) * 64);
            qf0 = __builtin_bit_cast(short8, q16[g]);
            qf1 = __builtin_bit_cast(short8, q16[4 + g]);
        }
        // ---- S^T = K · Q^T : 16 key-tiles x 2 k-steps ----
        f32x4 sacc[16];
#pragma unroll
        for (int t = 0; t < 16; ++t) sacc[t] = (f32x4){0.f, 0.f, 0.f, 0.f};
#pragma unroll
        for (int t = 0; t < 16; ++t) {
            const int key = t * 16 + lr;
            const int sw  = key & 7;
            short8 a0 = __builtin_bit_cast(short8, Ks16[key * 8 + (g ^ sw)]);
            short8 a1 = __builtin_bit_cast(short8, Ks16[key * 8 + ((4 + g) ^ sw)]);
            sacc[t] = __builtin_amdgcn_mfma_f32_16x16x32_bf16(a0, qf0, sacc[t], 0, 0, 0);
            sacc[t] = __builtin_amdgcn_mfma_f32_16x16x32_bf16(a1, qf1, sacc[t], 0, 0, 0);
        }
        // lane holds S^T[key = 16t + 4g + r][q-row = lr]
        // ---- softmax over keys (in-register + 2 shfl) ----
        float mx = -3.0e38f;
#pragma unroll
        for (int t = 0; t < 16; ++t) {
            mx = fmaxf(mx, fmaxf(fmaxf(sacc[t][0], sacc[t][1]),
                                 fmaxf(sacc[t][2], sacc[t][3])));
        }
        mx = fmaxf(mx, __shfl_xor(mx, 16));
        mx = fmaxf(mx, __shfl_xor(mx, 32));
        float lsum = 0.f;
#pragma unroll
        for (int t = 0; t < 16; ++t) {
            float p0 = exp2f((sacc[t][0] - mx) * cs);
            float p1 = exp2f((sacc[t][1] - mx) * cs);
            float p2 = exp2f((sacc[t][2] - mx) * cs);
            float p3 = exp2f((sacc[t][3] - mx) * cs);
            lsum += (p0 + p1) + (p2 + p3);
            unsigned int lo = f2bf(p0) | ((unsigned)f2bf(p1) << 16);
            unsigned int hi = f2bf(p2) | ((unsigned)f2bf(p3) << 16);
            // logical bytes: row lr, keys 16t+4g .. +3  -> block 2t+(g>>1), half g&1
            int pb = (2 * t + (g >> 1)) ^ (lr & 7);
            *(uint2*)(Pw + lr * 512 + pb * 16 + (g & 1) * 8) = make_uint2(lo, hi);
        }
        lsum += __shfl_xor(lsum, 16);
        lsum += __shfl_xor(lsum, 32);
        const float inv = 1.f / lsum;

        // ---- O = P · V : 8 k-steps, 2 ch-tiles ----
        f32x4 oacc0 = (f32x4){0.f, 0.f, 0.f, 0.f};
        f32x4 oacc1 = (f32x4){0.f, 0.f, 0.f, 0.f};
#pragma unroll
        for (int t = 0; t < 8; ++t) {
            const int pb = (4 * t + g);
            short8 pa = __builtin_bit_cast(short8,
                        *(const uint4*)(Pw + lr * 512 + ((pb ^ (lr & 7)) * 16)));
            short8 v0 = __builtin_bit_cast(short8, Vs16[lr * 32 + (pb ^ (lr & 7))]);
            short8 v1 = __builtin_bit_cast(short8, Vs16[(16 + lr) * 32 + (pb ^ (lr & 7))]);
            oacc0 = __builtin_amdgcn_mfma_f32_16x16x32_bf16(pa, v0, oacc0, 0, 0, 0);
            oacc1 = __builtin_amdgcn_mfma_f32_16x16x32_bf16(pa, v1, oacc1, 0, 0, 0);
        }
        // lane holds O[q-row = 4g + r][ch = nt*16 + lr]
        // ---- transpose O through LDS (reuse dead P region), coalesced store ----
        float* Ot = (float*)Pw;   // [32 ch][17] f32
#pragma unroll
        for (int r = 0; r < 4; ++r) Ot[lr * 17 + (g * 4 + r)] = oacc0[r];
#pragma unroll
        for (int r = 0; r < 4; ++r) Ot[(16 + lr) * 17 + (g * 4 + r)] = oacc1[r];

        float* outp = out + obase + (row0 + lr);
#pragma unroll
        for (int it = 0; it < 8; ++it) {
            int ch = it * 4 + g;
            float val = Ot[ch * 17 + lr] * inv * coef[ch];
            outp[(size_t)ch * HW] += val;
        }
    }
}

extern "C" void kernel_launch(void* const* d_in, const int* in_sizes, int n_in,
                              void* d_out, int out_size, void* d_ws, size_t ws_size,
                              hipStream_t stream) {
    (void)in_sizes; (void)n_in; (void)out_size; (void)ws_size;
    const float* xr    = (const float*)d_in[0];
    const float* xh    = (const float*)d_in[1];
    const float* lnw   = (const float*)d_in[2];
    const float* lnb   = (const float*)d_in[3];
    const float* wl1   = (const float*)d_in[4];
    const float* bl1   = (const float*)d_in[5];
    const float* wr1   = (const float*)d_in[6];
    const float* br1   = (const float*)d_in[7];
    const float* wl2   = (const float*)d_in[8];
    const float* bl2   = (const float*)d_in[9];
    const float* wr2   = (const float*)d_in[10];
    const float* br2   = (const float*)d_in[11];
    const float* wlres = (const float*)d_in[12];
    const float* blres = (const float*)d_in[13];
    const float* wrres = (const float*)d_in[14];
    const float* brres = (const float*)d_in[15];
    const float* beta  = (const float*)d_in[16];
    const float* gamma = (const float*)d_in[17];
    float* out = (float*)d_out;

    __hip_bfloat16* ql = (__hip_bfloat16*)d_ws;
    __hip_bfloat16* qr = ql + (size_t)1024 * 16384;
    __hip_bfloat16* vl = qr + (size_t)1024 * 16384;
    __hip_bfloat16* vr = vl + (size_t)1024 * 8192;

    proj_kernel<<<dim3(1024), dim3(256), 0, stream>>>(
        xr, xh, lnw, lnb, wl1, bl1, wr1, br1, wl2, bl2, wr2, br2,
        wlres, blres, wrres, brres, ql, qr, vl, vr, out);
    attn_kernel<<<dim3(1024, 2), dim3(256), 0, stream>>>(
        ql, qr, vl, vr, beta, gamma, out);
}

// Round 3
// 223.299 us; speedup vs baseline: 5.8687x; 2.1126x over previous
//
#include <hip/hip_runtime.h>
#include <hip/hip_bf16.h>

#define HW 65536

typedef short short8 __attribute__((ext_vector_type(8)));
typedef float f32x4 __attribute__((ext_vector_type(4)));

__device__ __forceinline__ unsigned short f2bf(float x) {
    return __builtin_bit_cast(unsigned short, __float2bfloat16(x));
}
__device__ __forceinline__ f32x4 mfma16(short8 a, short8 b, f32x4 c) {
    return __builtin_amdgcn_mfma_f32_16x16x32_bf16(a, b, c, 0, 0, 0);
}

// ---------------- weight prep (one block) ----------------
// wpack (bf16): [0]Wql'(64x64, W*lnw) [4096]Wqr [8192]Wvl [10240]Wvr
//               [12288]Wrl [14336]Wrr    st (f32): s[64], t[64]
__global__ __launch_bounds__(256) void prep_kernel(
    const float* __restrict__ wl1, const float* __restrict__ bl1,
    const float* __restrict__ wr1,
    const float* __restrict__ wl2, const float* __restrict__ wr2,
    const float* __restrict__ wlres, const float* __restrict__ wrres,
    const float* __restrict__ lnw, const float* __restrict__ lnb,
    __hip_bfloat16* __restrict__ wpack, float* __restrict__ st)
{
    const int tid = threadIdx.x;
    if (tid < 64) {
        const int o = tid;
        float s = 0.f, t = 0.f;
        for (int c = 0; c < 64; ++c) {
            __hip_bfloat16 wb = __float2bfloat16(wl1[o*64+c] * lnw[c]);
            wpack[o*64+c] = wb;
            s += __bfloat162float(wb);
            t += wl1[o*64+c] * lnb[c];
        }
        st[o] = s;
        st[64+o] = t + bl1[o];
    } else if (tid < 128) {
        const int o = tid - 64;
        for (int c = 0; c < 64; ++c) wpack[4096 + o*64+c] = __float2bfloat16(wr1[o*64+c]);
    } else if (tid < 160) {
        const int o = tid - 128;
        for (int c = 0; c < 64; ++c) wpack[8192 + o*64+c] = __float2bfloat16(wl2[o*64+c]);
    } else if (tid < 192) {
        const int o = tid - 160;
        for (int c = 0; c < 64; ++c) wpack[10240 + o*64+c] = __float2bfloat16(wr2[o*64+c]);
    } else if (tid < 224) {
        const int o = tid - 192;
        for (int c = 0; c < 64; ++c) wpack[12288 + o*64+c] = __float2bfloat16(wlres[o*64+c]);
    } else {
        const int o = tid - 224;
        for (int c = 0; c < 64; ++c) wpack[14336 + o*64+c] = __float2bfloat16(wrres[o*64+c]);
    }
}

// ---------------- fused proj + bidirectional attention ----------------
// LDS: QL[0,32K) QR[32K,64K) VL[64K,80K) VR[80K,96K) X/P[96K,128K) AUX[128K..)
//   q: px-major [256px][64ch] bf16, 16B-block cb at px*8 + (cb^(px&7))
//   v: ch-major [32ch][256px] bf16, 16B-block vb at ch*32 + (vb^(ch&7))
#define QL_OFF 0
#define QR_OFF 32768
#define VL_OFF 65536
#define VR_OFF 81920
#define XP_OFF 98304
#define AUX_OFF 131072
#define SMEM_BYTES (131072 + 3584)

__global__ __launch_bounds__(256) void fused_kernel(
    const float* __restrict__ xg_l, const float* __restrict__ xg_r,
    const __hip_bfloat16* __restrict__ wpack, const float* __restrict__ st,
    const float* __restrict__ bqr_g, const float* __restrict__ bl2,
    const float* __restrict__ br2, const float* __restrict__ blres,
    const float* __restrict__ brres, const float* __restrict__ beta,
    const float* __restrict__ gamma, float* __restrict__ out)
{
    __shared__ __align__(16) unsigned char smem[SMEM_BYTES];

    const int bh = blockIdx.x;
    const int b = bh >> 8, h = bh & 255;
    const int tid = threadIdx.x;
    const int wv = tid >> 6, lane = tid & 63;
    const int g = lane >> 4, lr = lane & 15;

    float* aArr  = (float*)(smem + AUX_OFF);          // rstd per px
    float* bbArr = (float*)(smem + AUX_OFF + 1024);   // -rstd*mu per px
    float* sArr  = (float*)(smem + AUX_OFF + 2048);
    float* tArr  = (float*)(smem + AUX_OFF + 2304);
    float* bqrA  = (float*)(smem + AUX_OFF + 2560);
    float* bvA   = (float*)(smem + AUX_OFF + 2816);
    float* bresA = (float*)(smem + AUX_OFF + 3072);
    float* coefA = (float*)(smem + AUX_OFF + 3328);

    const size_t obase = (size_t)b * 64 * HW + (size_t)h * 256;

    // ---- load both x rows into registers (coalesced, deep MLP of loads) ----
    const size_t xbase = obase + tid;
    float xl[64], xrr[64];
#pragma unroll
    for (int c = 0; c < 64; ++c) xl[c] = xg_l[xbase + (size_t)c * HW];
#pragma unroll
    for (int c = 0; c < 64; ++c) xrr[c] = xg_r[xbase + (size_t)c * HW];

    if (tid < 64) {
        sArr[tid] = st[tid];
        tArr[tid] = st[64 + tid];
        bqrA[tid] = bqr_g[tid];
        bvA[tid]  = tid < 32 ? bl2[tid]   : br2[tid - 32];
        bresA[tid]= tid < 32 ? blres[tid] : brres[tid - 32];
        coefA[tid]= tid < 32 ? beta[tid]  : gamma[tid - 32];
    }

    // ---- LN stats (f32) for left pixel tid ----
    float sum = 0.f;
#pragma unroll
    for (int c = 0; c < 64; ++c) sum += xl[c];
    const float mu = sum * (1.f / 64.f);
    float var = 0.f;
#pragma unroll
    for (int c = 0; c < 64; ++c) { float d = xl[c] - mu; var = fmaf(d, d, var); }
    const float rstd = rsqrtf(var * (1.f / 64.f) + 1e-6f);
    aArr[tid] = rstd;
    bbArr[tid] = -rstd * mu;

    // ---- stage X_left px-major bf16 swizzled ----
    uint4* X16 = (uint4*)(smem + XP_OFF);
#pragma unroll
    for (int cb = 0; cb < 8; ++cb) {
        uint4 u;
        u.x = f2bf(xl[cb*8+0]) | ((unsigned)f2bf(xl[cb*8+1]) << 16);
        u.y = f2bf(xl[cb*8+2]) | ((unsigned)f2bf(xl[cb*8+3]) << 16);
        u.z = f2bf(xl[cb*8+4]) | ((unsigned)f2bf(xl[cb*8+5]) << 16);
        u.w = f2bf(xl[cb*8+6]) | ((unsigned)f2bf(xl[cb*8+7]) << 16);
        X16[tid*8 + (cb ^ (tid & 7))] = u;
    }
    __syncthreads();

    const uint4* W16 = (const uint4*)wpack;

    // proj one side: q (4 Mtiles), v (2), res (2) over this wave's 4 px-tiles
    auto proj_side = [&](int wq, int wvv, int wr, unsigned char* qdst,
                         unsigned char* vdst, int chbase, bool ln) {
        short8 bfr0[4], bfr1[4];
#pragma unroll
        for (int i = 0; i < 4; ++i) {
            int px = (wv*4 + i)*16 + lr;
            bfr0[i] = __builtin_bit_cast(short8, X16[px*8 + (g ^ (px&7))]);
            bfr1[i] = __builtin_bit_cast(short8, X16[px*8 + ((4+g) ^ (px&7))]);
        }
        // ---- q ----
#pragma unroll
        for (int ot = 0; ot < 4; ++ot) {
            const int out0 = ot * 16;
            short8 af0 = __builtin_bit_cast(short8, W16[wq + (out0+lr)*8 + g]);
            short8 af1 = __builtin_bit_cast(short8, W16[wq + (out0+lr)*8 + 4 + g]);
            const int ch0 = out0 + 4*g;
            f32x4 c1 = *(const f32x4*)&(ln ? sArr : bqrA)[ch0];
            f32x4 c2 = ln ? *(const f32x4*)&tArr[ch0] : (f32x4){0.f,0.f,0.f,0.f};
#pragma unroll
            for (int i = 0; i < 4; ++i) {
                f32x4 acc = {0.f,0.f,0.f,0.f};
                acc = mfma16(af0, bfr0[i], acc);
                acc = mfma16(af1, bfr1[i], acc);
                const int px = (wv*4+i)*16 + lr;
                float q0,q1,q2,q3;
                if (ln) {
                    const float a_ = aArr[px], b_ = bbArr[px];
                    q0 = fmaf(a_, acc[0], fmaf(b_, c1[0], c2[0]));
                    q1 = fmaf(a_, acc[1], fmaf(b_, c1[1], c2[1]));
                    q2 = fmaf(a_, acc[2], fmaf(b_, c1[2], c2[2]));
                    q3 = fmaf(a_, acc[3], fmaf(b_, c1[3], c2[3]));
                } else {
                    q0 = acc[0]+c1[0]; q1 = acc[1]+c1[1];
                    q2 = acc[2]+c1[2]; q3 = acc[3]+c1[3];
                }
                unsigned lo = f2bf(q0) | ((unsigned)f2bf(q1) << 16);
                unsigned hi = f2bf(q2) | ((unsigned)f2bf(q3) << 16);
                *(uint2*)(qdst + px*128 + (((ch0>>3) ^ (px&7))*16) + (ch0&7)*2)
                    = make_uint2(lo, hi);
            }
        }
        // ---- v ----
#pragma unroll
        for (int ot = 0; ot < 2; ++ot) {
            const int out0 = ot * 16;
            short8 af0 = __builtin_bit_cast(short8, W16[wvv + (out0+lr)*8 + g]);
            short8 af1 = __builtin_bit_cast(short8, W16[wvv + (out0+lr)*8 + 4 + g]);
            const int ch0 = out0 + 4*g;
            f32x4 bv = *(const f32x4*)&bvA[chbase + ch0];
#pragma unroll
            for (int i = 0; i < 4; ++i) {
                f32x4 acc = {0.f,0.f,0.f,0.f};
                acc = mfma16(af0, bfr0[i], acc);
                acc = mfma16(af1, bfr1[i], acc);
                const int px = (wv*4+i)*16 + lr;
#pragma unroll
                for (int r = 0; r < 4; ++r) {
                    const int ch = ch0 + r;
                    *(unsigned short*)(vdst + ch*512 + (((px>>3) ^ (ch&7))*16) + (px&7)*2)
                        = f2bf(acc[r] + bv[r]);
                }
            }
        }
        // ---- res -> global ----
#pragma unroll
        for (int ot = 0; ot < 2; ++ot) {
            const int out0 = ot * 16;
            short8 af0 = __builtin_bit_cast(short8, W16[wr + (out0+lr)*8 + g]);
            short8 af1 = __builtin_bit_cast(short8, W16[wr + (out0+lr)*8 + 4 + g]);
            const int ch0 = out0 + 4*g;
            f32x4 bz = *(const f32x4*)&bresA[chbase + ch0];
#pragma unroll
            for (int i = 0; i < 4; ++i) {
                f32x4 acc = {0.f,0.f,0.f,0.f};
                acc = mfma16(af0, bfr0[i], acc);
                acc = mfma16(af1, bfr1[i], acc);
                const int px = (wv*4+i)*16 + lr;
                float* op = out + obase + px + (size_t)(chbase + ch0) * HW;
#pragma unroll
                for (int r = 0; r < 4; ++r) op[(size_t)r * HW] = acc[r] + bz[r];
            }
        }
    };

    proj_side(0, 1024, 1536, smem + QL_OFF, smem + VL_OFF, 0, true);
    __syncthreads();

    // ---- stage X_right ----
#pragma unroll
    for (int cb = 0; cb < 8; ++cb) {
        uint4 u;
        u.x = f2bf(xrr[cb*8+0]) | ((unsigned)f2bf(xrr[cb*8+1]) << 16);
        u.y = f2bf(xrr[cb*8+2]) | ((unsigned)f2bf(xrr[cb*8+3]) << 16);
        u.z = f2bf(xrr[cb*8+4]) | ((unsigned)f2bf(xrr[cb*8+5]) << 16);
        u.w = f2bf(xrr[cb*8+6]) | ((unsigned)f2bf(xrr[cb*8+7]) << 16);
        X16[tid*8 + (cb ^ (tid & 7))] = u;
    }
    __syncthreads();

    proj_side(512, 1280, 1792, smem + QR_OFF, smem + VR_OFF, 32, false);
    __syncthreads();   // res stores drained; X region becomes P

    // ---------------- attention, both directions ----------------
    unsigned char* Pw = smem + XP_OFF + wv * 8192;
    const float cs = 0.125f * 1.44269504088896f;   // scale * log2(e)

    for (int dir = 0; dir < 2; ++dir) {
        const uint4* Q16 = (const uint4*)(smem + (dir ? QR_OFF : QL_OFF));
        const uint4* K16 = (const uint4*)(smem + (dir ? QL_OFF : QR_OFF));
        const uint4* V16 = (const uint4*)(smem + (dir ? VL_OFF : VR_OFF));
        const float* coef = coefA + dir * 32;

        for (int c = 0; c < 4; ++c) {
            const int row0 = c * 64 + wv * 16;
            const int qpx = row0 + lr;
            short8 qf0 = __builtin_bit_cast(short8, Q16[qpx*8 + (g ^ (qpx&7))]);
            short8 qf1 = __builtin_bit_cast(short8, Q16[qpx*8 + ((4+g) ^ (qpx&7))]);

            f32x4 sacc[16];
#pragma unroll
            for (int t = 0; t < 16; ++t) sacc[t] = (f32x4){0.f,0.f,0.f,0.f};
#pragma unroll
            for (int t = 0; t < 16; ++t) {
                const int key = t * 16 + lr;
                const int sw = key & 7;
                short8 a0 = __builtin_bit_cast(short8, K16[key*8 + (g ^ sw)]);
                short8 a1 = __builtin_bit_cast(short8, K16[key*8 + ((4+g) ^ sw)]);
                sacc[t] = mfma16(a0, qf0, sacc[t]);
                sacc[t] = mfma16(a1, qf1, sacc[t]);
            }
            // softmax over keys (rows of S^T live across lanes 16/32-apart)
            float mx = -3.0e38f;
#pragma unroll
            for (int t = 0; t < 16; ++t)
                mx = fmaxf(mx, fmaxf(fmaxf(sacc[t][0], sacc[t][1]),
                                     fmaxf(sacc[t][2], sacc[t][3])));
            mx = fmaxf(mx, __shfl_xor(mx, 16));
            mx = fmaxf(mx, __shfl_xor(mx, 32));
            float lsum = 0.f;
#pragma unroll
            for (int t = 0; t < 16; ++t) {
                float p0 = exp2f((sacc[t][0] - mx) * cs);
                float p1 = exp2f((sacc[t][1] - mx) * cs);
                float p2 = exp2f((sacc[t][2] - mx) * cs);
                float p3 = exp2f((sacc[t][3] - mx) * cs);
                lsum += (p0 + p1) + (p2 + p3);
                unsigned lo = f2bf(p0) | ((unsigned)f2bf(p1) << 16);
                unsigned hi = f2bf(p2) | ((unsigned)f2bf(p3) << 16);
                int pb = (2*t + (g >> 1)) ^ (lr & 7);
                *(uint2*)(Pw + lr*512 + pb*16 + (g & 1)*8) = make_uint2(lo, hi);
            }
            lsum += __shfl_xor(lsum, 16);
            lsum += __shfl_xor(lsum, 32);
            const float inv = 1.f / lsum;

            f32x4 o0 = (f32x4){0.f,0.f,0.f,0.f};
            f32x4 o1 = (f32x4){0.f,0.f,0.f,0.f};
#pragma unroll
            for (int t = 0; t < 8; ++t) {
                const int pb = 4*t + g;
                short8 pa = __builtin_bit_cast(short8,
                            *(const uint4*)(Pw + lr*512 + ((pb ^ (lr&7))*16)));
                short8 v0 = __builtin_bit_cast(short8, V16[lr*32 + (pb ^ (lr&7))]);
                short8 v1 = __builtin_bit_cast(short8, V16[(16+lr)*32 + (pb ^ (lr&7))]);
                o0 = mfma16(pa, v0, o0);
                o1 = mfma16(pa, v1, o1);
            }
            // transpose O through (dead) P, coalesced accumulate to out
            float* Ot = (float*)Pw;
#pragma unroll
            for (int r = 0; r < 4; ++r) Ot[lr*17 + (g*4 + r)] = o0[r];
#pragma unroll
            for (int r = 0; r < 4; ++r) Ot[(16+lr)*17 + (g*4 + r)] = o1[r];

            float* outp = out + obase + (size_t)(dir*32) * HW + row0 + lr;
#pragma unroll
            for (int it = 0; it < 8; ++it) {
                const int ch = it*4 + g;
                outp[(size_t)ch * HW] += Ot[ch*17 + lr] * inv * coef[ch];
            }
        }
    }
}

extern "C" void kernel_launch(void* const* d_in, const int* in_sizes, int n_in,
                              void* d_out, int out_size, void* d_ws, size_t ws_size,
                              hipStream_t stream) {
    (void)in_sizes; (void)n_in; (void)out_size; (void)ws_size;
    const float* xr    = (const float*)d_in[0];
    const float* xh    = (const float*)d_in[1];
    const float* lnw   = (const float*)d_in[2];
    const float* lnb   = (const float*)d_in[3];
    const float* wl1   = (const float*)d_in[4];
    const float* bl1   = (const float*)d_in[5];
    const float* wr1   = (const float*)d_in[6];
    const float* br1   = (const float*)d_in[7];
    const float* wl2   = (const float*)d_in[8];
    const float* bl2   = (const float*)d_in[9];
    const float* wr2   = (const float*)d_in[10];
    const float* br2   = (const float*)d_in[11];
    const float* wlres = (const float*)d_in[12];
    const float* blres = (const float*)d_in[13];
    const float* wrres = (const float*)d_in[14];
    const float* brres = (const float*)d_in[15];
    const float* beta  = (const float*)d_in[16];
    const float* gamma = (const float*)d_in[17];
    float* out = (float*)d_out;

    __hip_bfloat16* wpack = (__hip_bfloat16*)d_ws;
    float* st = (float*)((unsigned char*)d_ws + 32768);

    prep_kernel<<<dim3(1), dim3(256), 0, stream>>>(
        wl1, bl1, wr1, wl2, wr2, wlres, wrres, lnw, lnb, wpack, st);
    fused_kernel<<<dim3(1024), dim3(256), 0, stream>>>(
        xr, xh, wpack, st, br1, bl2, br2, blres, brres, beta, gamma, out);
}

// Round 4
// 131.469 us; speedup vs baseline: 9.9679x; 1.6985x over previous
//
#include <hip/hip_runtime.h>
#include <hip/hip_bf16.h>

#define HW 65536

typedef short short8 __attribute__((ext_vector_type(8)));
typedef float f32x4 __attribute__((ext_vector_type(4)));

__device__ __forceinline__ unsigned short f2bf(float x) {
    return __builtin_bit_cast(unsigned short, __float2bfloat16(x));
}
__device__ __forceinline__ f32x4 mfma16(short8 a, short8 b, f32x4 c) {
    return __builtin_amdgcn_mfma_f32_16x16x32_bf16(a, b, c, 0, 0, 0);
}

// ---------------- weight prep (one block) ----------------
// wpack (bf16): [0]Wql'(64x64, W*lnw) [4096]Wqr [8192]Wvl [10240]Wvr
//               [12288]Wrl [14336]Wrr    st (f32): s[64], t[64]
__global__ __launch_bounds__(256) void prep_kernel(
    const float* __restrict__ wl1, const float* __restrict__ bl1,
    const float* __restrict__ wr1,
    const float* __restrict__ wl2, const float* __restrict__ wr2,
    const float* __restrict__ wlres, const float* __restrict__ wrres,
    const float* __restrict__ lnw, const float* __restrict__ lnb,
    __hip_bfloat16* __restrict__ wpack, float* __restrict__ st)
{
    const int tid = threadIdx.x;
    if (tid < 64) {
        const int o = tid;
        float s = 0.f, t = 0.f;
        for (int c = 0; c < 64; ++c) {
            __hip_bfloat16 wb = __float2bfloat16(wl1[o*64+c] * lnw[c]);
            wpack[o*64+c] = wb;
            s += __bfloat162float(wb);
            t += wl1[o*64+c] * lnb[c];
        }
        st[o] = s;
        st[64+o] = t + bl1[o];
    } else if (tid < 128) {
        const int o = tid - 64;
        for (int c = 0; c < 64; ++c) wpack[4096 + o*64+c] = __float2bfloat16(wr1[o*64+c]);
    } else if (tid < 160) {
        const int o = tid - 128;
        for (int c = 0; c < 64; ++c) wpack[8192 + o*64+c] = __float2bfloat16(wl2[o*64+c]);
    } else if (tid < 192) {
        const int o = tid - 160;
        for (int c = 0; c < 64; ++c) wpack[10240 + o*64+c] = __float2bfloat16(wr2[o*64+c]);
    } else if (tid < 224) {
        const int o = tid - 192;
        for (int c = 0; c < 64; ++c) wpack[12288 + o*64+c] = __float2bfloat16(wlres[o*64+c]);
    } else {
        const int o = tid - 224;
        for (int c = 0; c < 64; ++c) wpack[14336 + o*64+c] = __float2bfloat16(wrres[o*64+c]);
    }
}

// ---------------- fused proj + bidirectional attention ----------------
// LDS: QL[0,32K) QR[32K,64K) VL[64K,80K) VR[80K,96K) X/P[96K,128K) AUX[128K..)
//   q: px-major [256px][64ch] bf16, 16B-block cb at px*8 + (cb^(px&7))
//   v: ch-major [32ch][256px] bf16, 16B-block vb at ch*32 + (vb^(ch&7))
//   P: per-wave 4K, [16 row][128 key] bf16, block pb at row*16 + (pb^(row&7))
#define QL_OFF 0
#define QR_OFF 32768
#define VL_OFF 65536
#define VR_OFF 81920
#define XP_OFF 98304
#define AUX_OFF 131072
#define SMEM_BYTES (131072 + 7680)

__global__ __launch_bounds__(512, 2) void fused_kernel(
    const float* __restrict__ xg_l, const float* __restrict__ xg_r,
    const __hip_bfloat16* __restrict__ wpack, const float* __restrict__ st,
    const float* __restrict__ bqr_g, const float* __restrict__ bl2,
    const float* __restrict__ br2, const float* __restrict__ blres,
    const float* __restrict__ brres, const float* __restrict__ beta,
    const float* __restrict__ gamma, float* __restrict__ out)
{
    __shared__ __align__(16) unsigned char smem[SMEM_BYTES];

    const int bh = blockIdx.x;
    const int b = bh >> 8, h = bh & 255;
    const int tid = threadIdx.x;
    const int wv = tid >> 6, lane = tid & 63;
    const int g = lane >> 4, lr = lane & 15;
    const int px = tid & 255, half = tid >> 8;

    float* aArr  = (float*)(smem + AUX_OFF);          // rstd per px (1K)
    float* bbArr = (float*)(smem + AUX_OFF + 1024);   // -rstd*mu per px (1K)
    float* sArr  = (float*)(smem + AUX_OFF + 2048);
    float* tArr  = (float*)(smem + AUX_OFF + 2304);
    float* bqrA  = (float*)(smem + AUX_OFF + 2560);
    float* bvA   = (float*)(smem + AUX_OFF + 2816);
    float* bresA = (float*)(smem + AUX_OFF + 3072);
    float* coefA = (float*)(smem + AUX_OFF + 3328);
    float* pS    = (float*)(smem + AUX_OFF + 3584);   // 2K
    float* pQ    = (float*)(smem + AUX_OFF + 5632);   // 2K

    const size_t obase = (size_t)b * 64 * HW + (size_t)h * 256;
    const size_t xbase = obase + px;

    // ---- each thread loads 32 channels of both x rows (coalesced) ----
    float xl[32], xr_[32];
#pragma unroll
    for (int c = 0; c < 32; ++c) xl[c] = xg_l[xbase + (size_t)(half*32 + c) * HW];
#pragma unroll
    for (int c = 0; c < 32; ++c) xr_[c] = xg_r[xbase + (size_t)(half*32 + c) * HW];

    if (tid < 64) {
        sArr[tid] = st[tid];
        tArr[tid] = st[64 + tid];
        bqrA[tid] = bqr_g[tid];
        bvA[tid]  = tid < 32 ? bl2[tid]   : br2[tid - 32];
        bresA[tid]= tid < 32 ? blres[tid] : brres[tid - 32];
        coefA[tid]= tid < 32 ? beta[tid]  : gamma[tid - 32];
    }

    // ---- LN partial stats for left row ----
    {
        float s = 0.f, q = 0.f;
#pragma unroll
        for (int c = 0; c < 32; ++c) { s += xl[c]; q = fmaf(xl[c], xl[c], q); }
        pS[half*256 + px] = s;
        pQ[half*256 + px] = q;
    }

    // ---- stage X_left px-major bf16 swizzled (this thread's 32 ch) ----
    uint4* X16 = (uint4*)(smem + XP_OFF);
#pragma unroll
    for (int cb = 0; cb < 4; ++cb) {
        uint4 u;
        u.x = f2bf(xl[cb*8+0]) | ((unsigned)f2bf(xl[cb*8+1]) << 16);
        u.y = f2bf(xl[cb*8+2]) | ((unsigned)f2bf(xl[cb*8+3]) << 16);
        u.z = f2bf(xl[cb*8+4]) | ((unsigned)f2bf(xl[cb*8+5]) << 16);
        u.w = f2bf(xl[cb*8+6]) | ((unsigned)f2bf(xl[cb*8+7]) << 16);
        X16[px*8 + ((half*4 + cb) ^ (px & 7))] = u;
    }
    __syncthreads();
    if (half == 0) {
        float s = pS[px] + pS[256 + px];
        float q = pQ[px] + pQ[256 + px];
        float mu = s * (1.f / 64.f);
        float var = q * (1.f / 64.f) - mu * mu;
        float rstd = rsqrtf(var + 1e-6f);
        aArr[px] = rstd;
        bbArr[px] = -rstd * mu;
    }
    __syncthreads();

    const uint4* W16 = (const uint4*)wpack;

    // proj one side: q (4 Mtiles), v (2), res (2) over this wave's 2 px-tiles
    auto proj_side = [&](int wq, int wvv, int wr, unsigned char* qdst,
                         unsigned char* vdst, int chbase, bool ln) {
        short8 bfr0[2], bfr1[2];
#pragma unroll
        for (int i = 0; i < 2; ++i) {
            int p = (wv*2 + i)*16 + lr;
            bfr0[i] = __builtin_bit_cast(short8, X16[p*8 + (g ^ (p&7))]);
            bfr1[i] = __builtin_bit_cast(short8, X16[p*8 + ((4+g) ^ (p&7))]);
        }
        // ---- q: D[ch][px] ----
#pragma unroll
        for (int ot = 0; ot < 4; ++ot) {
            const int out0 = ot * 16;
            short8 af0 = __builtin_bit_cast(short8, W16[wq + (out0+lr)*8 + g]);
            short8 af1 = __builtin_bit_cast(short8, W16[wq + (out0+lr)*8 + 4 + g]);
            const int ch0 = out0 + 4*g;
            f32x4 c1 = *(const f32x4*)&(ln ? sArr : bqrA)[ch0];
            f32x4 c2 = ln ? *(const f32x4*)&tArr[ch0] : (f32x4){0.f,0.f,0.f,0.f};
#pragma unroll
            for (int i = 0; i < 2; ++i) {
                f32x4 acc = {0.f,0.f,0.f,0.f};
                acc = mfma16(af0, bfr0[i], acc);
                acc = mfma16(af1, bfr1[i], acc);
                const int p = (wv*2+i)*16 + lr;
                float q0,q1,q2,q3;
                if (ln) {
                    const float a_ = aArr[p], b_ = bbArr[p];
                    q0 = fmaf(a_, acc[0], fmaf(b_, c1[0], c2[0]));
                    q1 = fmaf(a_, acc[1], fmaf(b_, c1[1], c2[1]));
                    q2 = fmaf(a_, acc[2], fmaf(b_, c1[2], c2[2]));
                    q3 = fmaf(a_, acc[3], fmaf(b_, c1[3], c2[3]));
                } else {
                    q0 = acc[0]+c1[0]; q1 = acc[1]+c1[1];
                    q2 = acc[2]+c1[2]; q3 = acc[3]+c1[3];
                }
                unsigned lo = f2bf(q0) | ((unsigned)f2bf(q1) << 16);
                unsigned hi = f2bf(q2) | ((unsigned)f2bf(q3) << 16);
                *(uint2*)(qdst + p*128 + (((ch0>>3) ^ (p&7))*16) + (ch0&7)*2)
                    = make_uint2(lo, hi);
            }
        }
        // ---- v: swapped operands -> D[px][ch], 8B store per tile ----
#pragma unroll
        for (int ot = 0; ot < 2; ++ot) {
            const int out0 = ot * 16;
            short8 af0 = __builtin_bit_cast(short8, W16[wvv + (out0+lr)*8 + g]);
            short8 af1 = __builtin_bit_cast(short8, W16[wvv + (out0+lr)*8 + 4 + g]);
            const int ch = out0 + lr;               // this lane's channel
            const float bv = bvA[chbase + ch];
#pragma unroll
            for (int i = 0; i < 2; ++i) {
                f32x4 acc = {0.f,0.f,0.f,0.f};
                acc = mfma16(bfr0[i], af0, acc);
                acc = mfma16(bfr1[i], af1, acc);
                // lane holds px = (wv*2+i)*16 + 4g + r for r=0..3
                unsigned lo = f2bf(acc[0]+bv) | ((unsigned)f2bf(acc[1]+bv) << 16);
                unsigned hi = f2bf(acc[2]+bv) | ((unsigned)f2bf(acc[3]+bv) << 16);
                const int vb = (wv*2+i)*2 + (g>>1);
                *(uint2*)(vdst + ch*512 + ((vb ^ (ch&7))*16) + (g&1)*8)
                    = make_uint2(lo, hi);
            }
        }
        // ---- res -> global: D[ch][px] ----
#pragma unroll
        for (int ot = 0; ot < 2; ++ot) {
            const int out0 = ot * 16;
            short8 af0 = __builtin_bit_cast(short8, W16[wr + (out0+lr)*8 + g]);
            short8 af1 = __builtin_bit_cast(short8, W16[wr + (out0+lr)*8 + 4 + g]);
            const int ch0 = out0 + 4*g;
            f32x4 bz = *(const f32x4*)&bresA[chbase + ch0];
#pragma unroll
            for (int i = 0; i < 2; ++i) {
                f32x4 acc = {0.f,0.f,0.f,0.f};
                acc = mfma16(af0, bfr0[i], acc);
                acc = mfma16(af1, bfr1[i], acc);
                const int p = (wv*2+i)*16 + lr;
                float* op = out + obase + p + (size_t)(chbase + ch0) * HW;
#pragma unroll
                for (int r = 0; r < 4; ++r) op[(size_t)r * HW] = acc[r] + bz[r];
            }
        }
    };

    proj_side(0, 1024, 1536, smem + QL_OFF, smem + VL_OFF, 0, true);
    __syncthreads();

    // ---- stage X_right ----
#pragma unroll
    for (int cb = 0; cb < 4; ++cb) {
        uint4 u;
        u.x = f2bf(xr_[cb*8+0]) | ((unsigned)f2bf(xr_[cb*8+1]) << 16);
        u.y = f2bf(xr_[cb*8+2]) | ((unsigned)f2bf(xr_[cb*8+3]) << 16);
        u.z = f2bf(xr_[cb*8+4]) | ((unsigned)f2bf(xr_[cb*8+5]) << 16);
        u.w = f2bf(xr_[cb*8+6]) | ((unsigned)f2bf(xr_[cb*8+7]) << 16);
        X16[px*8 + ((half*4 + cb) ^ (px & 7))] = u;
    }
    __syncthreads();

    proj_side(512, 1280, 1792, smem + QR_OFF, smem + VR_OFF, 32, false);
    __syncthreads();   // all q/v in LDS, res stores issued; X region becomes P

    // ---------------- attention: waves 0-3 dir0, waves 4-7 dir1 ----------------
    unsigned char* Pw = smem + XP_OFF + wv * 4096;
    const int dir = wv >> 2, wsub = wv & 3;
    const float cs = 0.125f * 1.44269504088896f;   // scale * log2(e)

    const uint4* Q16 = (const uint4*)(smem + (dir ? QR_OFF : QL_OFF));
    const uint4* K16 = (const uint4*)(smem + (dir ? QL_OFF : QR_OFF));
    const uint4* V16 = (const uint4*)(smem + (dir ? VL_OFF : VR_OFF));
    const float* coef = coefA + dir * 32;

    for (int c = 0; c < 4; ++c) {
        const int row0 = c * 64 + wsub * 16;
        const int qpx = row0 + lr;
        short8 qf0 = __builtin_bit_cast(short8, Q16[qpx*8 + (g ^ (qpx&7))]);
        short8 qf1 = __builtin_bit_cast(short8, Q16[qpx*8 + ((4+g) ^ (qpx&7))]);

        f32x4 sacc[16];
#pragma unroll
        for (int t = 0; t < 16; ++t) sacc[t] = (f32x4){0.f,0.f,0.f,0.f};
#pragma unroll
        for (int t = 0; t < 16; ++t) {
            const int key = t * 16 + lr;
            const int sw = key & 7;
            short8 a0 = __builtin_bit_cast(short8, K16[key*8 + (g ^ sw)]);
            short8 a1 = __builtin_bit_cast(short8, K16[key*8 + ((4+g) ^ sw)]);
            sacc[t] = mfma16(a0, qf0, sacc[t]);
            sacc[t] = mfma16(a1, qf1, sacc[t]);
        }
        // lane holds S^T[key = 16t + 4g + r][q-row = lr]
        float mx = -3.0e38f;
#pragma unroll
        for (int t = 0; t < 16; ++t)
            mx = fmaxf(mx, fmaxf(fmaxf(sacc[t][0], sacc[t][1]),
                                 fmaxf(sacc[t][2], sacc[t][3])));
        mx = fmaxf(mx, __shfl_xor(mx, 16));
        mx = fmaxf(mx, __shfl_xor(mx, 32));

        float lsum = 0.f;
        f32x4 o0 = (f32x4){0.f,0.f,0.f,0.f};
        f32x4 o1 = (f32x4){0.f,0.f,0.f,0.f};
#pragma unroll
        for (int hh = 0; hh < 2; ++hh) {
            // exp + pack + write this half's P (16 rows x 128 keys, 4K)
#pragma unroll
            for (int t8 = 0; t8 < 8; ++t8) {
                const int t16 = hh * 8 + t8;
                float p0 = exp2f((sacc[t16][0] - mx) * cs);
                float p1 = exp2f((sacc[t16][1] - mx) * cs);
                float p2 = exp2f((sacc[t16][2] - mx) * cs);
                float p3 = exp2f((sacc[t16][3] - mx) * cs);
                lsum += (p0 + p1) + (p2 + p3);
                unsigned lo = f2bf(p0) | ((unsigned)f2bf(p1) << 16);
                unsigned hi = f2bf(p2) | ((unsigned)f2bf(p3) << 16);
                int pb = (2*t8 + (g >> 1)) ^ (lr & 7);
                *(uint2*)(Pw + lr*256 + pb*16 + (g & 1)*8) = make_uint2(lo, hi);
            }
            // PV over this half's 128 keys
#pragma unroll
            for (int t = 0; t < 4; ++t) {
                const int pb = 4*t + g;
                const int vb = 16*hh + 4*t + g;
                short8 pa = __builtin_bit_cast(short8,
                            *(const uint4*)(Pw + lr*256 + ((pb ^ (lr&7))*16)));
                short8 v0 = __builtin_bit_cast(short8, V16[lr*32 + (vb ^ (lr&7))]);
                short8 v1 = __builtin_bit_cast(short8, V16[(16+lr)*32 + (vb ^ (lr&7))]);
                o0 = mfma16(pa, v0, o0);
                o1 = mfma16(pa, v1, o1);
            }
        }
        lsum += __shfl_xor(lsum, 16);
        lsum += __shfl_xor(lsum, 32);
        const float inv = 1.f / lsum;

        // transpose O through (dead) P, coalesced accumulate to out
        float* Ot = (float*)Pw;
#pragma unroll
        for (int r = 0; r < 4; ++r) Ot[lr*17 + (g*4 + r)] = o0[r];
#pragma unroll
        for (int r = 0; r < 4; ++r) Ot[(16+lr)*17 + (g*4 + r)] = o1[r];

        float* outp = out + obase + (size_t)(dir*32) * HW + row0 + lr;
#pragma unroll
        for (int it = 0; it < 8; ++it) {
            const int ch = it*4 + g;
            outp[(size_t)ch * HW] += Ot[ch*17 + lr] * inv * coef[ch];
        }
    }
}

extern "C" void kernel_launch(void* const* d_in, const int* in_sizes, int n_in,
                              void* d_out, int out_size, void* d_ws, size_t ws_size,
                              hipStream_t stream) {
    (void)in_sizes; (void)n_in; (void)out_size; (void)ws_size;
    const float* xr    = (const float*)d_in[0];
    const float* xh    = (const float*)d_in[1];
    const float* lnw   = (const float*)d_in[2];
    const float* lnb   = (const float*)d_in[3];
    const float* wl1   = (const float*)d_in[4];
    const float* bl1   = (const float*)d_in[5];
    const float* wr1   = (const float*)d_in[6];
    const float* br1   = (const float*)d_in[7];
    const float* wl2   = (const float*)d_in[8];
    const float* bl2   = (const float*)d_in[9];
    const float* wr2   = (const float*)d_in[10];
    const float* br2   = (const float*)d_in[11];
    const float* wlres = (const float*)d_in[12];
    const float* blres = (const float*)d_in[13];
    const float* wrres = (const float*)d_in[14];
    const float* brres = (const float*)d_in[15];
    const float* beta  = (const float*)d_in[16];
    const float* gamma = (const float*)d_in[17];
    float* out = (float*)d_out;

    __hip_bfloat16* wpack = (__hip_bfloat16*)d_ws;
    float* st = (float*)((unsigned char*)d_ws + 32768);

    prep_kernel<<<dim3(1), dim3(256), 0, stream>>>(
        wl1, bl1, wr1, wl2, wr2, wlres, wrres, lnw, lnb, wpack, st);
    fused_kernel<<<dim3(1024), dim3(512), 0, stream>>>(
        xr, xh, wpack, st, br1, bl2, br2, blres, brres, beta, gamma, out);
}